// Round 9
// baseline (143.264 us; speedup 1.0000x reference)
//
#include <hip/hip_runtime.h>
#include <hip/hip_fp16.h>

#define HH 128
#define NB 4
#define NVOX (NB * HH * HH * HH)   // 8,388,608 = 2^23 voxels per image

// pass1 v3: lane holds d = {2*lane, 2*lane+1} (float2) -> one wave spans the
// full d-axis (no chunk seam). Block = 4 waves = 4 adjacent w-columns.
// Each wave slides 18 h-rows (16 outputs) of one w-column.
#define NBLK1 2048                 // img2 * b4 * hstrip8 * wgroup32
#define GRID2 512
#define TPB 256

// Slot arrays: every slot written by pass1 every call before pass2 reads them
// (dispatch-boundary ordering). No init kernel, no atomics on these.
__device__ __align__(16) unsigned int g_bmin[NBLK1];
__device__ __align__(16) unsigned int g_bmax[NBLK1];

union U4H8 { uint4 u; __half2 h[4]; };

// ---------------------------------------------------------------------------
// Pass 1 v3 (register/shfl, float2-per-lane, no LDS): separable Sobel magnitude.
// Ops per axis: s=(1,2,1), d=(-1,0,1), u=(1,1,1).
//   Sx=Gssd Sy=Gsds Sz=Gdss ; Sd11=Gsud-Gsdu Sd12=Gsud+Gsdu
//   Sd21=Gdus-Guds Sd22=Gdus+Guds ; Sd31=Gusd-Gdsu Sd32=Gusd+Gdsu
// Reflect pad=1: -1 -> 1, 128 -> 126. h,w wave-uniform; d via lane-selects:
//   out d=2i   : L = lane i-1 .y (lane0: own .y = q[1], reflect)
//   out d=2i+1 : R = lane i+1 .x (lane63: own .x = q[126], reflect)
// ---------------------------------------------------------------------------
__global__ __launch_bounds__(256) void pass1_kernel(
    const float* __restrict__ x, const float* __restrict__ y,
    __half* __restrict__ magx, __half* __restrict__ magy,
    float* __restrict__ out) {
    int bid = blockIdx.x;
    int tid = threadIdx.x;
    if (bid == 0 && tid == 0) out[0] = 0.0f;   // poison-clear for pass2 atomics

    int lane = tid & 63, wid = tid >> 6;
    int wg  = bid & 31;
    int hs  = (bid >> 5) & 7;
    int b   = (bid >> 8) & 3;
    int img = bid >> 10;

    const float* __restrict__ src = img ? y : x;
    __half* __restrict__ dst = img ? magy : magx;

    int w  = wg * 4 + wid;
    int wm = (w == 0) ? 1 : (w - 1);
    int wp = (w == 127) ? 126 : (w + 1);
    int h0 = hs << 4;
    const float2* base2 = (const float2*)(src + ((size_t)b << 21));

    // ring state: float2 per slot (components = two d positions)
    float2 sbD[3], ubD[3], dbS[3], sbS[3], ubS[3], dbU[3], sbU[3];
    float mn = 3.4e38f, mx = 0.0f;
    bool l0 = (lane == 0), l63 = (lane == 63);

    // c-stage along d for one column value q=(q[2i],q[2i+1]):
    // S/D/U for both components; 2 shuffles + 2 selects.
    auto cstage = [&](float2 q, float2& S, float2& D, float2& U) {
        float Lxs = __shfl_up(q.y, 1);
        float Rys = __shfl_down(q.x, 1);
        float Lx = l0  ? q.y : Lxs;    // d=2i-1 (reflect at d=0 -> q[1])
        float Ry = l63 ? q.x : Rys;    // d=2i+2 (reflect at d=127 -> q[126])
        float tx = Lx + q.y;
        float ty = q.x + Ry;
        S.x = fmaf(2.0f, q.x, tx);
        S.y = fmaf(2.0f, q.y, ty);
        D.x = q.y - Lx;
        D.y = Ry - q.x;
        U.x = tx + q.x;
        U.y = ty + q.y;
    };

#pragma unroll
    for (int r = 0; r < 18; ++r) {
        int hr = h0 + r - 1;
        hr = (hr < 0) ? 1 : ((hr > 127) ? 126 : hr);
        const float2* rm = base2 + (((hr << 7) + wm) << 6);
        const float2* rc = base2 + (((hr << 7) + w)  << 6);
        const float2* rp = base2 + (((hr << 7) + wp) << 6);
        float2 qm = rm[lane], qc = rc[lane], qp = rp[lane];

        float2 S0, D0, U0, S1, D1, U1, S2, D2, U2;
        cstage(qm, S0, D0, U0);
        cstage(qc, S1, D1, U1);
        cstage(qp, S2, D2, U2);

        int slot = r % 3;
        float2 tD = { D0.x + D2.x, D0.y + D2.y };
        sbD[slot] = { fmaf(2.0f, D1.x, tD.x), fmaf(2.0f, D1.y, tD.y) };
        ubD[slot] = { tD.x + D1.x, tD.y + D1.y };
        float2 tS = { S0.x + S2.x, S0.y + S2.y };
        sbS[slot] = { fmaf(2.0f, S1.x, tS.x), fmaf(2.0f, S1.y, tS.y) };
        ubS[slot] = { tS.x + S1.x, tS.y + S1.y };
        dbS[slot] = { S2.x - S0.x, S2.y - S0.y };
        float2 tU = { U0.x + U2.x, U0.y + U2.y };
        sbU[slot] = { fmaf(2.0f, U1.x, tU.x), fmaf(2.0f, U1.y, tU.y) };
        dbU[slot] = { U2.x - U0.x, U2.y - U0.y };

        if (r >= 2) {
            int s0 = (r - 2) % 3, s1 = (r - 1) % 3, s2 = slot;
            float2 m2;
#pragma unroll
            for (int c = 0; c < 2; ++c) {
                float vsbD0 = c ? sbD[s0].y : sbD[s0].x;
                float vsbD1 = c ? sbD[s1].y : sbD[s1].x;
                float vsbD2 = c ? sbD[s2].y : sbD[s2].x;
                float vubD0 = c ? ubD[s0].y : ubD[s0].x;
                float vubD1 = c ? ubD[s1].y : ubD[s1].x;
                float vubD2 = c ? ubD[s2].y : ubD[s2].x;
                float vdbS0 = c ? dbS[s0].y : dbS[s0].x;
                float vdbS1 = c ? dbS[s1].y : dbS[s1].x;
                float vdbS2 = c ? dbS[s2].y : dbS[s2].x;
                float vsbS0 = c ? sbS[s0].y : sbS[s0].x;
                float vsbS2 = c ? sbS[s2].y : sbS[s2].x;
                float vubS0 = c ? ubS[s0].y : ubS[s0].x;
                float vubS2 = c ? ubS[s2].y : ubS[s2].x;
                float vdbU0 = c ? dbU[s0].y : dbU[s0].x;
                float vdbU1 = c ? dbU[s1].y : dbU[s1].x;
                float vdbU2 = c ? dbU[s2].y : dbU[s2].x;
                float vsbU0 = c ? sbU[s0].y : sbU[s0].x;
                float vsbU2 = c ? sbU[s2].y : sbU[s2].x;

                float tsbD = vsbD0 + vsbD2;
                float Gssd = fmaf(2.0f, vsbD1, tsbD);
                float Gusd = tsbD + vsbD1;
                float tubD = vubD0 + vubD2;
                float Gsud = fmaf(2.0f, vubD1, tubD);
                float tdbS = vdbS0 + vdbS2;
                float Gsds = fmaf(2.0f, vdbS1, tdbS);
                float Guds = tdbS + vdbS1;
                float Gdss = vsbS2 - vsbS0;
                float Gdus = vubS2 - vubS0;
                float tdbU = vdbU0 + vdbU2;
                float Gsdu = fmaf(2.0f, vdbU1, tdbU);
                float Gdsu = vsbU2 - vsbU0;

                float f0 = Gssd;
                float f1 = Gsds;
                float f2 = Gdss;
                float f3 = Gsud - Gsdu;
                float f4 = Gsud + Gsdu;
                float f5 = Gdus - Guds;
                float f6 = Gdus + Guds;
                float f7 = Gusd - Gdsu;
                float f8 = Gusd + Gdsu;

                const float e1 = 1e-6f;
                float s = 9.0f * 1e-6f;
                float u;
                u = f0 + e1; s = fmaf(u, u, s);
                u = f1 + e1; s = fmaf(u, u, s);
                u = f2 + e1; s = fmaf(u, u, s);
                u = f3 + e1; s = fmaf(u, u, s);
                u = f4 + e1; s = fmaf(u, u, s);
                u = f5 + e1; s = fmaf(u, u, s);
                u = f6 + e1; s = fmaf(u, u, s);
                u = f7 + e1; s = fmaf(u, u, s);
                u = f8 + e1; s = fmaf(u, u, s);
                float m = sqrtf(s);
                if (c) m2.y = m; else m2.x = m;
            }

            __half2 hm2 = __float22half2_rn(m2);
            float2 mr = __half22float2(hm2);
            int hout = h0 + r - 2;
            // half2 index: (((b*128+hout)*128 + w) * 128 + 2*lane) / 2
            int h2idx = (((b * 128 + hout) * 128 + w) << 6) + lane;
            __builtin_nontemporal_store(*(unsigned int*)&hm2,
                (unsigned int*)((__half2*)dst + h2idx));
            mn = fminf(mn, fminf(mr.x, mr.y));
            mx = fmaxf(mx, fmaxf(mr.x, mr.y));
        }
    }

    // Block min/max reduce (uint trick valid: m > 0), plain store to unique slot
    unsigned int umn = __float_as_uint(mn);
    unsigned int umx = __float_as_uint(mx);
#pragma unroll
    for (int off = 32; off > 0; off >>= 1) {
        unsigned int a1 = __shfl_down(umn, off, 64);
        unsigned int b1 = __shfl_down(umx, off, 64);
        umn = (a1 < umn) ? a1 : umn;
        umx = (b1 > umx) ? b1 : umx;
    }
    __shared__ unsigned int smn[4], smx[4];
    if (lane == 0) { smn[wid] = umn; smx[wid] = umx; }
    __syncthreads();
    if (tid == 0) {
        unsigned int m0 = smn[0] < smn[1] ? smn[0] : smn[1];
        unsigned int m1 = smn[2] < smn[3] ? smn[2] : smn[3];
        unsigned int x0 = smx[0] > smx[1] ? smx[0] : smx[1];
        unsigned int x1 = smx[2] > smx[3] ? smx[2] : smx[3];
        g_bmin[bid] = (m0 < m1 ? m0 : m1);
        g_bmax[bid] = (x0 > x1 ? x0 : x1);
    }
}

// ---------------------------------------------------------------------------
// Pass 2 (R7-proven structure; slots now 2048): every block redundantly
// reduces the 16 KB of min/max slots (LLC-resident; no fences), streams its
// sequential shard of both fp16 mag arrays, one pre-scaled atomicAdd(out).
// ---------------------------------------------------------------------------
__global__ __launch_bounds__(TPB) void pass2_kernel(
    const uint4* __restrict__ magx8, const uint4* __restrict__ magy8,
    float* __restrict__ out) {
    int tid = threadIdx.x, bid = blockIdx.x;
    int lane = tid & 63, wid = tid >> 6;
    __shared__ unsigned int sred[4][4];
    __shared__ float smm[4];
    __shared__ float sv[4];

    // ---- redundant global min/max reduce: 1024 slots per image = 256 uint4 ----
    const uint4* bmin4 = (const uint4*)g_bmin;   // [0,256): img x, [256,512): img y
    const uint4* bmax4 = (const uint4*)g_bmax;
    uint4 a = bmin4[tid];
    uint4 b = bmax4[tid];
    uint4 c = bmin4[tid + 256];
    uint4 d = bmax4[tid + 256];
    unsigned int a01 = (a.x < a.y) ? a.x : a.y, a23 = (a.z < a.w) ? a.z : a.w;
    unsigned int b01 = (b.x > b.y) ? b.x : b.y, b23 = (b.z > b.w) ? b.z : b.w;
    unsigned int c01 = (c.x < c.y) ? c.x : c.y, c23 = (c.z < c.w) ? c.z : c.w;
    unsigned int d01 = (d.x > d.y) ? d.x : d.y, d23 = (d.z > d.w) ? d.z : d.w;
    unsigned int v0 = (a01 < a23) ? a01 : a23;
    unsigned int v1 = (b01 > b23) ? b01 : b23;
    unsigned int v2 = (c01 < c23) ? c01 : c23;
    unsigned int v3 = (d01 > d23) ? d01 : d23;
#pragma unroll
    for (int off = 32; off > 0; off >>= 1) {
        unsigned int t0 = __shfl_down(v0, off, 64);
        unsigned int t1 = __shfl_down(v1, off, 64);
        unsigned int t2 = __shfl_down(v2, off, 64);
        unsigned int t3 = __shfl_down(v3, off, 64);
        v0 = (t0 < v0) ? t0 : v0;
        v1 = (t1 > v1) ? t1 : v1;
        v2 = (t2 < v2) ? t2 : v2;
        v3 = (t3 > v3) ? t3 : v3;
    }
    if (lane == 0) { sred[wid][0] = v0; sred[wid][1] = v1; sred[wid][2] = v2; sred[wid][3] = v3; }
    __syncthreads();
    if (tid == 0) {
        unsigned int r0 = sred[0][0], r1 = sred[0][1], r2 = sred[0][2], r3 = sred[0][3];
#pragma unroll
        for (int w = 1; w < 4; ++w) {
            r0 = (sred[w][0] < r0) ? sred[w][0] : r0;
            r1 = (sred[w][1] > r1) ? sred[w][1] : r1;
            r2 = (sred[w][2] < r2) ? sred[w][2] : r2;
            r3 = (sred[w][3] > r3) ? sred[w][3] : r3;
        }
        smm[0] = __uint_as_float(r0);
        smm[1] = __uint_as_float(r1);
        smm[2] = __uint_as_float(r2);
        smm[3] = __uint_as_float(r3);
    }
    __syncthreads();

    // ---- normalize + L1 partial sum over this block's sequential shard ----
    float mnx = smm[0], mxx = smm[1], mny = smm[2], mxy = smm[3];
    float ix = 1.0f / (mxx - mnx + 1e-6f);
    float iy = 1.0f / (mxy - mny + 1e-6f);
    float cx = -mnx * ix;
    float cy = -mny * iy;

    float s = 0.0f;
    // NVOX/8 = 1,048,576 uint4 per array; per block 2048 sequential uint4
#pragma unroll
    for (int k = 0; k < 8; ++k) {
        int i = bid * 2048 + k * TPB + tid;
        U4H8 qa, qb;
        qa.u = magx8[i];
        qb.u = magy8[i];
#pragma unroll
        for (int j = 0; j < 4; ++j) {
            float2 va = __half22float2(qa.h[j]);
            float2 vb = __half22float2(qb.h[j]);
            s += fabsf(fmaf(va.x, ix, cx) - fmaf(vb.x, iy, cy));
            s += fabsf(fmaf(va.y, ix, cx) - fmaf(vb.y, iy, cy));
        }
    }
#pragma unroll
    for (int off = 32; off > 0; off >>= 1) s += __shfl_down(s, off, 64);
    if (lane == 0) sv[wid] = s;
    __syncthreads();
    if (tid == 0) {
        float partial = ((sv[0] + sv[1]) + (sv[2] + sv[3])) * (1.0f / (float)NVOX); // *2^-23 exact
        if (bid == 0) partial += 1e-6f;
        atomicAdd(out, partial);
    }
}

extern "C" void kernel_launch(void* const* d_in, const int* in_sizes, int n_in,
                              void* d_out, int out_size, void* d_ws, size_t ws_size,
                              hipStream_t stream) {
    const float* x = (const float*)d_in[0];
    const float* y = (const float*)d_in[1];
    // d_in[2] = kernels (weights hardcoded via separable factorization)
    float* out = (float*)d_out;

    __half* magx = (__half*)d_ws;            // NVOX halfs (16 MiB)
    __half* magy = magx + NVOX;              // NVOX halfs (16 MiB)

    pass1_kernel<<<NBLK1, 256, 0, stream>>>(x, y, magx, magy, out);
    pass2_kernel<<<GRID2, TPB, 0, stream>>>((const uint4*)magx, (const uint4*)magy, out);
}